// Round 10
// baseline (4443.534 us; speedup 1.0000x reference)
//
#include <hip/hip_runtime.h>
#include <math.h>

// NestedOscillator — run-length (blind-add) pass1 + heaters + parallel replay.
//
// Model (fits R2-R9): a LONE wave retires ~4.2 cyc/instruction regardless of
// type/dependence -> minimize instructions/step. Slow period = exactly 125
// steps, fast = exactly 25 (2pi/(omega*dt)), so wraps are predictable: steps
// provably wrap-free run as ONE dependent v_add each; only ~3-5 steps/chunk
// near a predicted wrap run the full checked form. Cross-wave splits (R5/R9)
// are abandoned: sync costs exceed the split's savings.
//
// Bitwise-exactness (absmax must be 0; machinery verified R1-R9):
//  - np.mod(x,2pi), x in [0,4pi): conditional subtract is Sterbenz-exact;
//    x - (+0.0f) == x bitwise for all x here (values >= +0).
//  - blind step == checked step when no wrap: (x+d)-0.0f == fl(x+d) == x += d.
//  - conservative windows: blind region provably wrap-free:
//    iterated value after j adds <= x + j*d + j*ulp(8) (ulp(8)=9.54e-7);
//    slow: rem>=27 -> x + 24*ds + 2.3e-5 < Ts - 2.9*ds  (safe).
//    fast: pf = trunc((Tf-x)*inv_df)-2 -> x + (pf-1)*df < Tf - 0.7 (safe).
//    Estimate errors (fp32 mul) <= ~1e-5 relative: covered by the margin.
//  - threshold: fl(x+d) >= 2pi <=> x >= T (monotone; T by exact ulp-walk).
//  - crossed(t) == slow-wrap during step t-1 (proof in earlier rounds).
//  - reset: nf*k, k in [0,1]: product < 2pi -> reference's outer mod is
//    identity; *1.0f bit-exact (no denormals). Generic-k fmodf fallback kept.
//  - omega = (float)exp((double)log_omega) == numpy f32 exp (R1-R9).

#define TWO_PI_F 6.28318530717958647692f
#define K_STEPS  25
#define HEAT_OUTER 3000

// Exact min x with fl(x+d) >= TWO_PI_F (monotone predicate -> ulp-walk exact).
__device__ __forceinline__ float wrap_threshold(float d)
{
    float x = TWO_PI_F - d;
    for (int i = 0; i < 256 && (x + d >= TWO_PI_F); ++i)
        x = __uint_as_float(__float_as_uint(x) - 1u);
    for (int i = 0; i < 256 && (x + d < TWO_PI_F); ++i)
        x = __uint_as_float(__float_as_uint(x) + 1u);
    return x;
}

__global__ void osc_clear(unsigned* __restrict__ done)
{
    if (threadIdx.x == 0) *done = 0u;
}

__global__ __launch_bounds__(256, 1)
void osc_pass1(const float* __restrict__ lsw, const float* __restrict__ lfw,
               const float* __restrict__ rs,
               float* __restrict__ snapS, float* __restrict__ snapF,
               unsigned* __restrict__ flags, unsigned* __restrict__ done,
               int nchunk)
{
    if (blockIdx.x == 0) {
        if (threadIdx.x != 0) return;   // chain thread alone in its wave

        const float ws  = (float)exp((double)lsw[0]);
        const float wfq = (float)exp((double)lfw[0]);
        const float k   = 1.0f - rs[0];
        const float ds  = ws * 0.001f;
        const float df  = wfq * 0.001f;
        const float Ts  = wrap_threshold(ds);
        const float Tf  = wrap_threshold(df);
        const float inv_ds = 1.0f / ds;
        const float inv_df = 1.0f / df;
        const bool  k_ok = (k >= 0.0f && k <= 1.0f);

        float slow = 0.0f, fast = 0.0f;
        unsigned prev_fl = 0u;          // t=0: prev=0 -> no crossing

        for (int c = 0; c < nchunk; ++c) {
            snapS[c] = slow;
            snapF[c] = fast;

            // ---------- SLOW chain, 25 steps ----------
            unsigned fl = 0u;
            if ((Ts - slow) * inv_ds >= 27.0f) {
                // provably wrap-free: 25 blind adds (1 VALU each)
#pragma unroll
                for (int i = 0; i < K_STEPS; ++i) slow += ds;
            } else {
                // checked chunk (~1 in 5): verified threshold form
#pragma unroll
                for (int i = 0; i < K_STEPS; ++i) {
                    const bool wb = (slow >= Ts);
                    fl |= (wb ? 1u : 0u) << i;
                    const float amt = wb ? TWO_PI_F : 0.0f;
                    slow = (slow + ds) - amt;       // Sterbenz / -0 exact
                }
            }

            // ---------- FAST chain, 25 steps ----------
            // bit i of w == crossed at step 25c+i
            const unsigned w = (fl << 1) | (prev_fl >> (K_STEPS - 1));
            if (w == 0u) {
                int pf = (int)((Tf - fast) * inv_df) - 2;
                if (pf > K_STEPS) pf = K_STEPS;
                if (pf < 0) pf = 0;
                // blind run (Duff dispatch, 1 VALU/step)
                switch (pf) {
                    case 25: fast += df; [[fallthrough]];
                    case 24: fast += df; [[fallthrough]];
                    case 23: fast += df; [[fallthrough]];
                    case 22: fast += df; [[fallthrough]];
                    case 21: fast += df; [[fallthrough]];
                    case 20: fast += df; [[fallthrough]];
                    case 19: fast += df; [[fallthrough]];
                    case 18: fast += df; [[fallthrough]];
                    case 17: fast += df; [[fallthrough]];
                    case 16: fast += df; [[fallthrough]];
                    case 15: fast += df; [[fallthrough]];
                    case 14: fast += df; [[fallthrough]];
                    case 13: fast += df; [[fallthrough]];
                    case 12: fast += df; [[fallthrough]];
                    case 11: fast += df; [[fallthrough]];
                    case 10: fast += df; [[fallthrough]];
                    case 9:  fast += df; [[fallthrough]];
                    case 8:  fast += df; [[fallthrough]];
                    case 7:  fast += df; [[fallthrough]];
                    case 6:  fast += df; [[fallthrough]];
                    case 5:  fast += df; [[fallthrough]];
                    case 4:  fast += df; [[fallthrough]];
                    case 3:  fast += df; [[fallthrough]];
                    case 2:  fast += df; [[fallthrough]];
                    case 1:  fast += df; [[fallthrough]];
                    default: break;
                }
                // checked remainder (no reset possible: w == 0)
                for (int i = pf; i < K_STEPS; ++i) {
                    const float amt = (fast >= Tf) ? TWO_PI_F : 0.0f;
                    fast = (fast + df) - amt;
                }
            } else if (k_ok) {
                // reset chunk (~1 in 5): verified R3 per-step form
#pragma unroll
                for (int i = 0; i < K_STEPS; ++i) {
                    const float m   = ((w >> i) & 1u) ? k : 1.0f;
                    const float amt = (fast >= Tf) ? TWO_PI_F : 0.0f;
                    fast = ((fast + df) - amt) * m; // *1.0f bit-exact
                }
            } else {
                // ultra-safe generic-k fallback: literal reference semantics
                for (int i = 0; i < K_STEPS; ++i) {
                    float nf = fast + df;
                    if (nf >= TWO_PI_F) nf -= TWO_PI_F;
                    if ((w >> i) & 1u) nf = fmodf(nf * k, TWO_PI_F);
                    fast = nf;
                }
            }

            flags[c] = fl;
            prev_fl = fl;
        }
        __hip_atomic_store(done, 1u, __ATOMIC_RELEASE, __HIP_MEMORY_SCOPE_AGENT);
    } else {
        // ---- heater: keep clocks up (R7/R8, +10%); capped + flag-stopped ----
        float a0 = 1.00f + (float)(threadIdx.x & 7) * 0.125f;
        float a1 = 1.25f, a2 = 1.50f, a3 = 1.75f;
        const float b = 1.0000001f, cc = 1.0e-7f;
        for (int o = 0; o < HEAT_OUTER; ++o) {
#pragma unroll
            for (int i = 0; i < 256; ++i) {
                a0 = __builtin_fmaf(a0, b, cc);
                a1 = __builtin_fmaf(a1, b, cc);
                a2 = __builtin_fmaf(a2, b, cc);
                a3 = __builtin_fmaf(a3, b, cc);
            }
            asm volatile("" :: "v"(a0), "v"(a1), "v"(a2), "v"(a3));
            if (__hip_atomic_load(done, __ATOMIC_ACQUIRE,
                                  __HIP_MEMORY_SCOPE_AGENT))
                break;
        }
        asm volatile("" :: "v"(a0), "v"(a1), "v"(a2), "v"(a3));
    }
}

__global__ __launch_bounds__(256)
void osc_pass2(const float* __restrict__ lsw, const float* __restrict__ lfw,
               const float* __restrict__ rs,
               const float* __restrict__ snapS, const float* __restrict__ snapF,
               const unsigned* __restrict__ flags,
               float* __restrict__ out, int steps, int nchunk)
{
    const int c = blockIdx.x * blockDim.x + threadIdx.x;
    if (c >= nchunk) return;

    const float ws  = (float)exp((double)lsw[0]);
    const float wfq = (float)exp((double)lfw[0]);
    const float k   = 1.0f - rs[0];
    const float ds  = ws * 0.001f;
    const float df  = wfq * 0.001f;
    const float Ts  = wrap_threshold(ds);
    const float Tf  = wrap_threshold(df);
    const float inv2pi = 0.15915494309189533577f;

    float slow = snapS[c], fast = snapF[c];
    const unsigned fc = flags[c];
    const unsigned fp = (c > 0) ? flags[c - 1] : 0u;
    const unsigned w = (fc << 1) | (fp >> (K_STEPS - 1));

    float* __restrict__ o_slow = out;
    float* __restrict__ o_fast = out + steps;
    float* __restrict__ o_fis  = out + 2 * steps;
    const int base = c * K_STEPS;

#pragma unroll 5
    for (int i = 0; i < K_STEPS; ++i) {
        const int t = base + i;
        if (t < steps) {
            o_slow[t] = slow;
            o_fast[t] = fast;
            o_fis[t]  = slow * inv2pi;
        }
        const float m = ((w >> i) & 1u) ? k : 1.0f;
        const float amt_s = (slow >= Ts) ? TWO_PI_F : 0.0f;
        const float amt_f = (fast >= Tf) ? TWO_PI_F : 0.0f;
        slow = (slow + ds) - amt_s;
        fast = ((fast + df) - amt_f) * m;   // *1.0f bit-exact
    }
}

extern "C" void kernel_launch(void* const* d_in, const int* in_sizes, int n_in,
                              void* d_out, int out_size, void* d_ws, size_t ws_size,
                              hipStream_t stream)
{
    const float* lsw = (const float*)d_in[0];
    const float* lfw = (const float*)d_in[1];
    const float* rs  = (const float*)d_in[2];
    float* out = (float*)d_out;
    const int steps  = out_size / 3;                     // 100000
    const int nchunk = (steps + K_STEPS - 1) / K_STEPS;  // 4000

    // workspace: snapS | snapF | flags | done  (48 KB + 4)
    float*    snapS = (float*)d_ws;
    float*    snapF = snapS + nchunk;
    unsigned* flags = (unsigned*)(snapF + nchunk);
    unsigned* done  = flags + nchunk;

    hipLaunchKernelGGL(osc_clear, dim3(1), dim3(64), 0, stream, done);
    hipLaunchKernelGGL(osc_pass1, dim3(256), dim3(256), 0, stream,
                       lsw, lfw, rs, snapS, snapF, flags, done, nchunk);
    const int threads = 256;
    const int blocks = (nchunk + threads - 1) / threads;
    hipLaunchKernelGGL(osc_pass2, dim3(blocks), dim3(threads), 0, stream,
                       lsw, lfw, rs, snapS, snapF, flags, out, steps, nchunk);
}

// Round 11
// 3983.120 us; speedup vs baseline: 1.1156x; 1.1156x over previous
//
#include <hip/hip_runtime.h>
#include <math.h>

// NestedOscillator — 2-dep-level pipelined step (lookahead wrap flags) +
// heaters + parallel replay. Straight-line, fully unrolled, branchless:
// every dynamic-control variant (R4 __any, R5/R9 cross-wave, R10 switch)
// regressed; R3/R8 branchless forms won.
//
// Critical path per step (the experiment: 3 levels -> 2):
//   slow: x' = (x + ds) + namt          [add -> add]
//   fast: xf' = fma(xf + df, M, N)      [add -> fma]
// All selects/compares are >= 1 step AHEAD of use via lookahead thresholds:
//   W_{i+2} = !W_{i+1} & !W_i & (x_i >= T3s),  T3s = min x: fl(fl(x+d)+d) >= Ts
// (exact: monotone predicate, ulp-walk; wrap lands < d+ulp, can't re-reach
//  the threshold region within 2 steps since d < 1).
//
// Bitwise-exactness (absmax must be 0; verified machinery R1-R10):
//  - np.mod(x,2pi), x in [0,4pi): conditional -2pi is Sterbenz-exact;
//    t + (+0.0f) == t for t >= +0.
//  - omega = (float)exp((double)log_omega) == numpy f32 exp.
//  - crossed(t) == slow-wrap during step t-1.
//  - fused fast step (k==0.5 only; bitwise-verified in R5/R8):
//    fma(tf, M, N), M in {1,.5}, N in {0,-2pi,-pi}; all cases single-rounded
//    equal to ref's mod-then-mul (Sterbenz; tf*0.5 exact; tf*0.5-pi exact).
//  - fast lookahead recurrence Wf_{i+2} = cf_i & !Wf_{i+1} & !Wf_i &
//    !C_{i+1} & !C_i: post-wrap/post-reset values <= pi+df/2 < Tf2 for df<1
//    (gated); non-wrap path is the monotone 2-apply threshold.
//  - generic (k!=0.5 or weird d) fallback: R3 plain step, verified.

#define TWO_PI_F 6.28318530717958647692f
#define PI_F     3.14159265358979323846f
#define K_STEPS  25
#define HEAT_OUTER 3000

// Exact min x with fl(x+d) >= TWO_PI_F (monotone -> ulp-walk exact).
__device__ __forceinline__ float wrap_threshold(float d)
{
    float x = TWO_PI_F - d;
    for (int i = 0; i < 512 && (x + d >= TWO_PI_F); ++i)
        x = __uint_as_float(__float_as_uint(x) - 1u);
    for (int i = 0; i < 512 && (x + d < TWO_PI_F); ++i)
        x = __uint_as_float(__float_as_uint(x) + 1u);
    return x;
}

// Exact min x with fl(fl(x+d)+d) >= T (monotone composition -> exact walk).
__device__ __forceinline__ float wrap_threshold2(float d, float T)
{
    float x = (T - d) - d;
    for (int i = 0; i < 512 && (((x + d) + d) >= T); ++i)
        x = __uint_as_float(__float_as_uint(x) - 1u);
    for (int i = 0; i < 512 && (((x + d) + d) < T); ++i)
        x = __uint_as_float(__float_as_uint(x) + 1u);
    return x;
}

// Plain verified step (init, fallback, pass2).
__device__ __forceinline__ void step_state(float& slow, float& fast, bool& wrap,
                                           float ds, float df, float k)
{
    const bool  crossed = wrap;
    const float ts = slow + ds;
    const float us = ts - TWO_PI_F;
    const bool  w2 = (ts >= TWO_PI_F);
    const float tf = fast + df;
    const float uf = tf - TWO_PI_F;
    const bool  wfb = (tf >= TWO_PI_F);
    const float nf = wfb ? uf : tf;
    const float m  = crossed ? k : 1.0f;
    fast = nf * m;
    slow = w2 ? us : ts;
    wrap = w2;
}

__global__ void osc_clear(unsigned* __restrict__ done)
{
    if (threadIdx.x == 0) *done = 0u;
}

__global__ __launch_bounds__(256, 1)
void osc_pass1(const float* __restrict__ lsw, const float* __restrict__ lfw,
               const float* __restrict__ rs, float4* __restrict__ snap,
               unsigned* __restrict__ done, int nchunk)
{
    if (blockIdx.x == 0) {
        if (threadIdx.x != 0) return;    // chain thread alone

        const float ws  = (float)exp((double)lsw[0]);
        const float wfq = (float)exp((double)lfw[0]);
        const float k   = 1.0f - rs[0];
        const float ds  = ws * 0.001f;
        const float df  = wfq * 0.001f;

        const bool fused_ok = (k == 0.5f) && (ds > 0.0f) && (ds < 1.0f)
                                          && (df > 0.0f) && (df < 1.0f);
        if (fused_ok) {
            const float Ts  = wrap_threshold(ds);
            const float Tf  = wrap_threshold(df);
            const float T3s = wrap_threshold2(ds, Ts);
            const float Tf3 = wrap_threshold2(df, Tf);

            float x = 0.0f, xf = 0.0f;
            // pipeline init: W_{-1}, W_0, W_1 / Wf_0, Wf_1 via exact sim
            bool Wm1 = false;                       // t=0: prev=0, no crossing
            bool W0  = (x >= Ts);
            bool W1, Wf0 = (xf >= Tf), Wf1;
            {
                float s1 = x, f1 = xf; bool w = Wm1;
                step_state(s1, f1, w, ds, df, k);   // exact step 0
                W1  = (s1 >= Ts);
                Wf1 = (f1 >= Tf);
            }

            for (int c = 0; c < nchunk; ++c) {
                snap[c] = make_float4(x, xf, Wm1 ? 1.0f : 0.0f, 0.0f);
#pragma unroll
                for (int i = 0; i < K_STEPS; ++i) {
                    const bool cs = Wm1;            // crossed_i = W_{i-1}
                    // lookahead compares (entry values, 2 steps of slack)
                    const bool c2  = (x  >= T3s);
                    const bool cf2 = (xf >= Tf3);
                    // slow: 2-level chain
                    const float namt = W0 ? -TWO_PI_F : 0.0f;
                    const float t = x + ds;
                    x = t + namt;                   // Sterbenz / +0 exact
                    // fast: 2-level chain (selects off-path, >=1 lvl slack)
                    const float M    = cs  ? 0.5f   : 1.0f;
                    const float nsel = cs  ? -PI_F  : -TWO_PI_F;
                    const float N    = Wf0 ? nsel   : 0.0f;
                    const float tf = xf + df;
                    xf = __builtin_fmaf(tf, M, N);  // bitwise == mod-then-mul
                    // flag pipeline (SALU)
                    const bool W2  = c2  && !W1  && !W0;
                    const bool Wf2 = cf2 && !Wf1 && !Wf0 && !W0 && !cs;
                    Wm1 = W0; W0 = W1; W1 = W2;
                    Wf0 = Wf1; Wf1 = Wf2;
                }
            }
        } else {
            // generic fallback: plain verified form
            float slow = 0.0f, fast = 0.0f;
            bool wrap = false;
            for (int c = 0; c < nchunk; ++c) {
                snap[c] = make_float4(slow, fast, wrap ? 1.0f : 0.0f, 0.0f);
#pragma unroll
                for (int i = 0; i < K_STEPS; ++i)
                    step_state(slow, fast, wrap, ds, df, k);
            }
        }
        __hip_atomic_store(done, 1u, __ATOMIC_RELEASE, __HIP_MEMORY_SCOPE_AGENT);
    } else {
        // heater: keep clocks up (R7/R8, +10%); capped + flag-stopped
        float a0 = 1.00f + (float)(threadIdx.x & 7) * 0.125f;
        float a1 = 1.25f, a2 = 1.50f, a3 = 1.75f;
        const float b = 1.0000001f, cc = 1.0e-7f;
        for (int o = 0; o < HEAT_OUTER; ++o) {
#pragma unroll
            for (int i = 0; i < 256; ++i) {
                a0 = __builtin_fmaf(a0, b, cc);
                a1 = __builtin_fmaf(a1, b, cc);
                a2 = __builtin_fmaf(a2, b, cc);
                a3 = __builtin_fmaf(a3, b, cc);
            }
            asm volatile("" :: "v"(a0), "v"(a1), "v"(a2), "v"(a3));
            if (__hip_atomic_load(done, __ATOMIC_ACQUIRE,
                                  __HIP_MEMORY_SCOPE_AGENT))
                break;
        }
        asm volatile("" :: "v"(a0), "v"(a1), "v"(a2), "v"(a3));
    }
}

__global__ __launch_bounds__(256)
void osc_pass2(const float* __restrict__ lsw, const float* __restrict__ lfw,
               const float* __restrict__ rs, const float4* __restrict__ snap,
               float* __restrict__ out, int steps, int nchunk)
{
    const int c = blockIdx.x * blockDim.x + threadIdx.x;
    if (c >= nchunk) return;

    const float ws  = (float)exp((double)lsw[0]);
    const float wfr = (float)exp((double)lfw[0]);
    const float k   = 1.0f - rs[0];
    const float ds  = ws * 0.001f;
    const float df  = wfr * 0.001f;
    const float inv2pi = 0.15915494309189533577f;

    float4 s = snap[c];
    float slow = s.x, fast = s.y;
    bool wrap = (s.z != 0.0f);

    float* __restrict__ o_slow = out;
    float* __restrict__ o_fast = out + steps;
    float* __restrict__ o_fis  = out + 2 * steps;
    const int base = c * K_STEPS;

#pragma unroll 5
    for (int i = 0; i < K_STEPS; ++i) {
        const int t = base + i;
        o_slow[t] = slow;
        o_fast[t] = fast;
        o_fis[t]  = slow * inv2pi;
        step_state(slow, fast, wrap, ds, df, k);
    }
}

extern "C" void kernel_launch(void* const* d_in, const int* in_sizes, int n_in,
                              void* d_out, int out_size, void* d_ws, size_t ws_size,
                              hipStream_t stream)
{
    const float* lsw = (const float*)d_in[0];
    const float* lfw = (const float*)d_in[1];
    const float* rs  = (const float*)d_in[2];
    float* out = (float*)d_out;
    const int steps  = out_size / 3;                     // 100000
    const int nchunk = (steps + K_STEPS - 1) / K_STEPS;  // 4000

    float4*   snap = (float4*)d_ws;                      // 4000 * 16B = 64 KB
    unsigned* done = (unsigned*)((char*)d_ws + (size_t)nchunk * sizeof(float4));

    hipLaunchKernelGGL(osc_clear, dim3(1), dim3(64), 0, stream, done);
    hipLaunchKernelGGL(osc_pass1, dim3(256), dim3(256), 0, stream,
                       lsw, lfw, rs, snap, done, nchunk);
    const int threads = 256;
    const int blocks = (nchunk + threads - 1) / threads;
    hipLaunchKernelGGL(osc_pass2, dim3(blocks), dim3(threads), 0, stream,
                       lsw, lfw, rs, snap, out, steps, nchunk);
}

// Round 12
// 3446.387 us; speedup vs baseline: 1.2893x; 1.1557x over previous
//
#include <hip/hip_runtime.h>
#include <math.h>

// NestedOscillator — serial slow chain + SPECULATIVE-PARALLEL fast chain.
//
// Structure (model from R2-R11: lone-wave cost ~4 cyc/VALU-instr; branches
// and cross-wave sync regress; straight-line unrolled forms win):
//  K1 osc_slow : the ONLY irreducibly serial part — slow chain, 4 VALU/step
//                (cmp, cndmask, add, add), writes per-chunk slowS/crossW.
//                Heater blocks keep clocks up (R7: +10%).
//  K2 osc_fast : fast chain is CONTRACTED x0.5 at each theta-crossing (every
//                125 steps). 32 workgroups each compute 3125 output steps,
//                seeded with guess 0.0 WARM=4375 steps early (35 resets);
//                mantissa-difference halves per reset -> bitwise collapse to
//                the true trajectory. Writes fastS + exit claim[g].
//  K3 osc_verify: claim[g] must equal fastS[(g+1)*CPW] bitwise. Induction
//                from wg0 (true init) => all outputs exactly the serial chain.
//  K4 osc_fb   : if any mismatch: deterministic serial recompute of fastS
//                (R8-verified form). Correct either way; never runs in practice.
//  K5 osc_pass2: parallel replay of 25-step chunks -> 3 output streams.
//
// Bitwise-exactness (absmax must be 0; machinery verified R1-R11):
//  - np.mod(x,2pi), x in [0,4pi): conditional -2pi is Sterbenz-exact;
//    t + (+0.0f) == t for t >= +0.
//  - threshold: fl(x+d) >= 2pi <=> x >= T (monotone; T by exact ulp-walk).
//  - crossed(t) == slow-wrap during step t-1.
//  - fused fast step (k==0.5; bitwise-verified R5/R8): fma(tf, M, N),
//    M in {1,.5}, N in {0,-2pi,-pi}: all 4 cases single-rounded == reference
//    mod-then-mul (Sterbenz sub; tf*0.5 exact; tf*0.5-pi exact).
//  - generic k: R3 mul form for k in [0,1] (product < 2pi -> outer mod
//    identity); literal fmodf form otherwise.
//  - omega = (float)exp((double)log_omega) == numpy f32 exp (R1-R11).

#define TWO_PI_F 6.28318530717958647692f
#define PI_F     3.14159265358979323846f
#define K_STEPS  25
#define CPW      125     // chunks per fast workgroup (3125 steps)
#define WARM     175     // warmup chunks (4375 steps ~= 35 resets)
#define HEAT_OUTER 3000

// Exact min x with fl(x+d) >= TWO_PI_F (monotone predicate -> ulp-walk exact).
__device__ __forceinline__ float wrap_threshold(float d)
{
    float x = TWO_PI_F - d;
    for (int i = 0; i < 512 && (x + d >= TWO_PI_F); ++i)
        x = __uint_as_float(__float_as_uint(x) - 1u);
    for (int i = 0; i < 512 && (x + d < TWO_PI_F); ++i)
        x = __uint_as_float(__float_as_uint(x) + 1u);
    return x;
}

// Fused both-chain step, k==0.5 only (R8-verified bitwise).
__device__ __forceinline__ void step_fused(float& x, float& xf, bool& crossed,
                                           float ds, float df, float Ts, float Tf)
{
    const bool  cs   = crossed;
    const bool  wbs  = (x  >= Ts);
    const bool  wbf  = (xf >= Tf);
    const float namt = wbs ? -TWO_PI_F : 0.0f;
    const float M    = cs  ? 0.5f      : 1.0f;
    const float nsel = cs  ? -PI_F     : -TWO_PI_F;
    const float N    = wbf ? nsel      : 0.0f;
    x  = (x + ds) + namt;                     // Sterbenz / +0 exact
    xf = __builtin_fmaf(xf + df, M, N);       // bitwise == mod-then-mul
    crossed = wbs;
}

// Generic both-chain step (R2/R3-verified literal semantics, any k).
__device__ __forceinline__ void step_generic(float& x, float& xf, bool& crossed,
                                             float ds, float df, float k)
{
    const bool  cs = crossed;
    const float ts = x + ds;
    const bool  w2 = (ts >= TWO_PI_F);
    const float tf = xf + df;
    float nf = (tf >= TWO_PI_F) ? tf - TWO_PI_F : tf;
    if (cs) {
        float v = nf * k;
        if (v >= TWO_PI_F || v < 0.0f) v = fmodf(fmodf(v, TWO_PI_F) + TWO_PI_F, TWO_PI_F);
        nf = v;
    }
    x  = w2 ? ts - TWO_PI_F : ts;
    xf = nf;
    crossed = w2;
}

__global__ void osc_clear(unsigned* __restrict__ done, unsigned* __restrict__ bad)
{
    if (threadIdx.x == 0) { *done = 0u; *bad = 0u; }
}

// K1: serial slow chain (the only irreducible serial core) + heaters.
__global__ __launch_bounds__(256, 1)
void osc_slow(const float* __restrict__ lsw,
              float* __restrict__ slowS, unsigned* __restrict__ crossW,
              unsigned* __restrict__ done, int nchunk)
{
    if (blockIdx.x == 0) {
        if (threadIdx.x != 0) return;
        const float ws = (float)exp((double)lsw[0]);
        const float ds = ws * 0.001f;
        const float Ts = wrap_threshold(ds);

        float x = 0.0f;
        bool wrap = false;               // t=0: prev=0 -> no crossing
        for (int c = 0; c < nchunk; ++c) {
            slowS[c]  = x;
            crossW[c] = wrap ? 1u : 0u;
#pragma unroll
            for (int i = 0; i < K_STEPS; ++i) {
                const bool  wb   = (x >= Ts);
                const float namt = wb ? -TWO_PI_F : 0.0f;
                x = (x + ds) + namt;     // 2-add chain; cmp/sel off-chain
                wrap = wb;
            }
        }
        __hip_atomic_store(done, 1u, __ATOMIC_RELEASE, __HIP_MEMORY_SCOPE_AGENT);
    } else {
        // heater: keep clocks up (R7/R8: +10%); capped + flag-stopped
        float a0 = 1.00f + (float)(threadIdx.x & 7) * 0.125f;
        float a1 = 1.25f, a2 = 1.50f, a3 = 1.75f;
        const float b = 1.0000001f, cc = 1.0e-7f;
        for (int o = 0; o < HEAT_OUTER; ++o) {
#pragma unroll
            for (int i = 0; i < 256; ++i) {
                a0 = __builtin_fmaf(a0, b, cc);
                a1 = __builtin_fmaf(a1, b, cc);
                a2 = __builtin_fmaf(a2, b, cc);
                a3 = __builtin_fmaf(a3, b, cc);
            }
            asm volatile("" :: "v"(a0), "v"(a1), "v"(a2), "v"(a3));
            if (__hip_atomic_load(done, __ATOMIC_ACQUIRE,
                                  __HIP_MEMORY_SCOPE_AGENT))
                break;
        }
        asm volatile("" :: "v"(a0), "v"(a1), "v"(a2), "v"(a3));
    }
}

// K2: speculative-parallel fast chain. wg g outputs chunks [g*CPW,(g+1)*CPW),
// warming up from guess xf=0 starting WARM chunks early (exact collapse via
// x0.5 contraction at each crossing; verified by K3).
__global__ __launch_bounds__(64, 1)
void osc_fast(const float* __restrict__ lsw, const float* __restrict__ lfw,
              const float* __restrict__ rs,
              const float* __restrict__ slowS, const unsigned* __restrict__ crossW,
              float* __restrict__ fastS, float* __restrict__ claim, int nchunk)
{
    if (threadIdx.x != 0) return;
    const int g  = blockIdx.x;
    const int c0 = g * CPW;
    if (c0 >= nchunk) return;
    const int c1 = min(c0 + CPW, nchunk);
    const int sc = max(0, c0 - WARM);

    const float ws  = (float)exp((double)lsw[0]);
    const float wfq = (float)exp((double)lfw[0]);
    const float k   = 1.0f - rs[0];
    const float ds  = ws * 0.001f;
    const float df  = wfq * 0.001f;
    const float Ts  = wrap_threshold(ds);
    const float Tf  = wrap_threshold(df);

    float x = slowS[sc];
    bool crossed = (crossW[sc] != 0u);
    float xf = 0.0f;                     // guess; exact if sc == 0

    if (k == 0.5f) {
        for (int c = sc; c < c1; ++c) {
            if (c >= c0) fastS[c] = xf;
#pragma unroll
            for (int i = 0; i < K_STEPS; ++i)
                step_fused(x, xf, crossed, ds, df, Ts, Tf);
        }
    } else {
        for (int c = sc; c < c1; ++c) {
            if (c >= c0) fastS[c] = xf;
#pragma unroll
            for (int i = 0; i < K_STEPS; ++i)
                step_generic(x, xf, crossed, ds, df, k);
        }
    }
    claim[g] = xf;                       // state at entry of chunk c1
}

// K3: verify speculation boundaries (bitwise).
__global__ void osc_verify(const float* __restrict__ claim,
                           const float* __restrict__ fastS,
                           unsigned* __restrict__ bad, int nchunk, int nwg)
{
    const int g = threadIdx.x;
    if (g >= nwg) return;
    const int cb = (g + 1) * CPW;
    if (cb >= nchunk) return;            // last wg has no successor
    if (__float_as_uint(claim[g]) != __float_as_uint(fastS[cb]))
        atomicOr(bad, 1u);
}

// K4: deterministic serial fallback (only if verification failed).
__global__ __launch_bounds__(64, 1)
void osc_fb(const float* __restrict__ lsw, const float* __restrict__ lfw,
            const float* __restrict__ rs, const unsigned* __restrict__ bad,
            float* __restrict__ fastS, int nchunk)
{
    if (threadIdx.x != 0) return;
    if (*bad == 0u) return;

    const float ws  = (float)exp((double)lsw[0]);
    const float wfq = (float)exp((double)lfw[0]);
    const float k   = 1.0f - rs[0];
    const float ds  = ws * 0.001f;
    const float df  = wfq * 0.001f;
    const float Ts  = wrap_threshold(ds);
    const float Tf  = wrap_threshold(df);

    float x = 0.0f, xf = 0.0f;
    bool crossed = false;
    if (k == 0.5f) {
        for (int c = 0; c < nchunk; ++c) {
            fastS[c] = xf;
#pragma unroll
            for (int i = 0; i < K_STEPS; ++i)
                step_fused(x, xf, crossed, ds, df, Ts, Tf);
        }
    } else {
        for (int c = 0; c < nchunk; ++c) {
            fastS[c] = xf;
#pragma unroll
            for (int i = 0; i < K_STEPS; ++i)
                step_generic(x, xf, crossed, ds, df, k);
        }
    }
}

// K5: parallel replay -> outputs.
__global__ __launch_bounds__(256)
void osc_pass2(const float* __restrict__ lsw, const float* __restrict__ lfw,
               const float* __restrict__ rs,
               const float* __restrict__ slowS, const float* __restrict__ fastS,
               const unsigned* __restrict__ crossW,
               float* __restrict__ out, int steps, int nchunk)
{
    const int c = blockIdx.x * blockDim.x + threadIdx.x;
    if (c >= nchunk) return;

    const float ws  = (float)exp((double)lsw[0]);
    const float wfq = (float)exp((double)lfw[0]);
    const float k   = 1.0f - rs[0];
    const float ds  = ws * 0.001f;
    const float df  = wfq * 0.001f;
    const float Ts  = wrap_threshold(ds);
    const float Tf  = wrap_threshold(df);
    const float inv2pi = 0.15915494309189533577f;

    float x = slowS[c], xf = fastS[c];
    bool crossed = (crossW[c] != 0u);
    const bool fused = (k == 0.5f);

    float* __restrict__ o_slow = out;
    float* __restrict__ o_fast = out + steps;
    float* __restrict__ o_fis  = out + 2 * steps;
    const int base = c * K_STEPS;

#pragma unroll 5
    for (int i = 0; i < K_STEPS; ++i) {
        const int t = base + i;
        if (t < steps) {
            o_slow[t] = x;
            o_fast[t] = xf;
            o_fis[t]  = x * inv2pi;
        }
        if (fused) step_fused(x, xf, crossed, ds, df, Ts, Tf);
        else       step_generic(x, xf, crossed, ds, df, k);
    }
}

extern "C" void kernel_launch(void* const* d_in, const int* in_sizes, int n_in,
                              void* d_out, int out_size, void* d_ws, size_t ws_size,
                              hipStream_t stream)
{
    const float* lsw = (const float*)d_in[0];
    const float* lfw = (const float*)d_in[1];
    const float* rs  = (const float*)d_in[2];
    float* out = (float*)d_out;
    const int steps  = out_size / 3;                     // 100000
    const int nchunk = (steps + K_STEPS - 1) / K_STEPS;  // 4000
    const int nwg    = (nchunk + CPW - 1) / CPW;         // 32

    // workspace: slowS | fastS | crossW | claim[64] | done | bad
    float*    slowS  = (float*)d_ws;
    float*    fastS  = slowS + nchunk;
    unsigned* crossW = (unsigned*)(fastS + nchunk);
    float*    claim  = (float*)(crossW + nchunk);
    unsigned* done   = (unsigned*)(claim + 64);
    unsigned* bad    = done + 1;

    hipLaunchKernelGGL(osc_clear, dim3(1), dim3(64), 0, stream, done, bad);
    hipLaunchKernelGGL(osc_slow, dim3(256), dim3(256), 0, stream,
                       lsw, slowS, crossW, done, nchunk);
    hipLaunchKernelGGL(osc_fast, dim3(nwg), dim3(64), 0, stream,
                       lsw, lfw, rs, slowS, crossW, fastS, claim, nchunk);
    hipLaunchKernelGGL(osc_verify, dim3(1), dim3(64), 0, stream,
                       claim, fastS, bad, nchunk, nwg);
    hipLaunchKernelGGL(osc_fb, dim3(1), dim3(64), 0, stream,
                       lsw, lfw, rs, bad, fastS, nchunk);
    const int threads = 256;
    const int blocks = (nchunk + threads - 1) / threads;
    hipLaunchKernelGGL(osc_pass2, dim3(blocks), dim3(threads), 0, stream,
                       lsw, lfw, rs, slowS, fastS, crossW, out, steps, nchunk);
}

// Round 13
// 1752.573 us; speedup vs baseline: 2.5354x; 1.9665x over previous
//
#include <hip/hip_runtime.h>
#include <math.h>

// NestedOscillator — R8 two-pass structure + packed-f32 (VOP3P) serial step.
//
// Model (final; fits R2-R12): a lone wave is ISSUE-bound at ~4.2 cyc per
// instruction regardless of type/dependence. All parallel/speculative
// decompositions are dead: cross-wave sync costs > split savings (R5/R9),
// dynamic branches ~40cyc (R10), speculative fast-chain collapse is blocked
// by a deterministic ~1-ulp parity equilibrium (R12, osc_fb ran). Lever:
// instruction count. This round: {add,add}+{add,fma} -> v_pk_add_f32 +
// v_pk_fma_f32 (per-half IEEE fp32, bitwise identical), 10 -> ~8 instr/step.
//
// Bitwise-exactness (absmax must be 0; machinery verified R1-R12):
//  - np.mod(x,2pi), x in [0,4pi): conditional -2pi is Sterbenz-exact;
//    t + (+0.0f) == t for t >= +0.
//  - threshold trick (R4/R5-verified): fl(x+d) >= 2pi <=> x >= T, T by exact
//    monotone ulp-walk.
//  - crossed(t) == slow-wrap during step t-1.
//  - fused fast step (k==0.5 only; bitwise-verified R5/R8/R11/R12):
//    fma(tf, M, N), M in {1,.5}, N in {0,-2pi,-pi}: all cases single-rounded
//    equal to reference mod-then-mul (Sterbenz sub; tf*0.5 exact; tf*0.5-pi
//    exact). v_pk_fma_f32 halves are IEEE fma -> same bits.
//  - generic k fallback: R3/R8 scalar step (verified).
//  - omega = (float)exp((double)log_omega) == numpy f32 exp (R1-R12).

#define TWO_PI_F 6.28318530717958647692f
#define PI_F     3.14159265358979323846f
#define K_STEPS  25
#define HEAT_OUTER 3000

typedef float v2f __attribute__((ext_vector_type(2)));

// Exact min x with fl(x+d) >= TWO_PI_F (monotone predicate -> ulp-walk exact).
__device__ __forceinline__ float wrap_threshold(float d)
{
    float x = TWO_PI_F - d;
    for (int i = 0; i < 512 && (x + d >= TWO_PI_F); ++i)
        x = __uint_as_float(__float_as_uint(x) - 1u);
    for (int i = 0; i < 512 && (x + d < TWO_PI_F); ++i)
        x = __uint_as_float(__float_as_uint(x) + 1u);
    return x;
}

// Plain verified step (generic-k fallback + pass2; bitwise-verified R1-R12).
__device__ __forceinline__ void step_state(float& slow, float& fast, bool& wrap,
                                           float ds, float df, float k)
{
    const bool  crossed = wrap;
    const float ts = slow + ds;
    const float us = ts - TWO_PI_F;
    const bool  w2 = (ts >= TWO_PI_F);
    const float tf = fast + df;
    const float uf = tf - TWO_PI_F;
    const bool  wfb = (tf >= TWO_PI_F);
    const float nf = wfb ? uf : tf;
    const float m  = crossed ? k : 1.0f;
    fast = nf * m;
    slow = w2 ? us : ts;
    wrap = w2;
}

__global__ void osc_clear(unsigned* __restrict__ done)
{
    if (threadIdx.x == 0) *done = 0u;
}

__global__ __launch_bounds__(256, 1)
void osc_pass1(const float* __restrict__ lsw, const float* __restrict__ lfw,
               const float* __restrict__ rs, float4* __restrict__ snap,
               unsigned* __restrict__ done, int nchunk)
{
    if (blockIdx.x == 0) {
        if (threadIdx.x != 0) return;    // chain thread alone in its wave

        const float ws  = (float)exp((double)lsw[0]);
        const float wfq = (float)exp((double)lfw[0]);
        const float k   = 1.0f - rs[0];
        const float ds  = ws * 0.001f;
        const float df  = wfq * 0.001f;

        if (k == 0.5f) {
            const float Ts = wrap_threshold(ds);
            const float Tf = wrap_threshold(df);

            v2f S; S.x = 0.0f; S.y = 0.0f;
            v2f D; D.x = ds;   D.y = df;
            bool cs = false;             // crossed at current step

            for (int c = 0; c < nchunk; ++c) {
                snap[c] = make_float4(S.x, S.y, cs ? 1.0f : 0.0f, 0.0f);
#pragma unroll
                for (int i = 0; i < K_STEPS; ++i) {
                    // selects (cndmask) — off the packed chain
                    const float mf   = cs ? 0.5f  : 1.0f;
                    const float nsel = cs ? -PI_F : -TWO_PI_F;
                    const bool  wbs  = (S.x >= Ts);
                    const bool  wbf  = (S.y >= Tf);
                    const float nsv  = wbs ? -TWO_PI_F : 0.0f;
                    const float nfv  = wbf ? nsel      : 0.0f;
                    v2f M; M.x = 1.0f; M.y = mf;
                    v2f N; N.x = nsv;  N.y = nfv;
                    v2f T, Sn;
                    // packed fp32: per-half IEEE add/fma — bitwise identical
                    asm("v_pk_add_f32 %0, %1, %2"
                        : "=v"(T) : "v"(S), "v"(D));
                    asm("v_pk_fma_f32 %0, %1, %2, %3"
                        : "=v"(Sn) : "v"(T), "v"(M), "v"(N));
                    S = Sn;
                    cs = wbs;
                }
            }
        } else {
            // generic-k fallback: plain verified form
            float slow = 0.0f, fast = 0.0f;
            bool wrap = false;
            for (int c = 0; c < nchunk; ++c) {
                snap[c] = make_float4(slow, fast, wrap ? 1.0f : 0.0f, 0.0f);
#pragma unroll
                for (int i = 0; i < K_STEPS; ++i)
                    step_state(slow, fast, wrap, ds, df, k);
            }
        }
        __hip_atomic_store(done, 1u, __ATOMIC_RELEASE, __HIP_MEMORY_SCOPE_AGENT);
    } else {
        // heater: keep clocks up (R7/R8: +10%); capped + flag-stopped
        float a0 = 1.00f + (float)(threadIdx.x & 7) * 0.125f;
        float a1 = 1.25f, a2 = 1.50f, a3 = 1.75f;
        const float b = 1.0000001f, cc = 1.0e-7f;
        for (int o = 0; o < HEAT_OUTER; ++o) {
#pragma unroll
            for (int i = 0; i < 256; ++i) {
                a0 = __builtin_fmaf(a0, b, cc);
                a1 = __builtin_fmaf(a1, b, cc);
                a2 = __builtin_fmaf(a2, b, cc);
                a3 = __builtin_fmaf(a3, b, cc);
            }
            asm volatile("" :: "v"(a0), "v"(a1), "v"(a2), "v"(a3));
            if (__hip_atomic_load(done, __ATOMIC_ACQUIRE,
                                  __HIP_MEMORY_SCOPE_AGENT))
                break;
        }
        asm volatile("" :: "v"(a0), "v"(a1), "v"(a2), "v"(a3));
    }
}

__global__ __launch_bounds__(256)
void osc_pass2(const float* __restrict__ lsw, const float* __restrict__ lfw,
               const float* __restrict__ rs, const float4* __restrict__ snap,
               float* __restrict__ out, int steps, int nchunk)
{
    const int c = blockIdx.x * blockDim.x + threadIdx.x;
    if (c >= nchunk) return;

    const float ws  = (float)exp((double)lsw[0]);
    const float wfr = (float)exp((double)lfw[0]);
    const float k   = 1.0f - rs[0];
    const float ds  = ws * 0.001f;
    const float df  = wfr * 0.001f;
    const float inv2pi = 0.15915494309189533577f;

    float4 s = snap[c];
    float slow = s.x, fast = s.y;
    bool wrap = (s.z != 0.0f);

    float* __restrict__ o_slow = out;
    float* __restrict__ o_fast = out + steps;
    float* __restrict__ o_fis  = out + 2 * steps;
    const int base = c * K_STEPS;

#pragma unroll 5
    for (int i = 0; i < K_STEPS; ++i) {
        const int t = base + i;
        o_slow[t] = slow;
        o_fast[t] = fast;
        o_fis[t]  = slow * inv2pi;
        step_state(slow, fast, wrap, ds, df, k);
    }
}

extern "C" void kernel_launch(void* const* d_in, const int* in_sizes, int n_in,
                              void* d_out, int out_size, void* d_ws, size_t ws_size,
                              hipStream_t stream)
{
    const float* lsw = (const float*)d_in[0];
    const float* lfw = (const float*)d_in[1];
    const float* rs  = (const float*)d_in[2];
    float* out = (float*)d_out;
    const int steps  = out_size / 3;                     // 100000
    const int nchunk = (steps + K_STEPS - 1) / K_STEPS;  // 4000

    float4*   snap = (float4*)d_ws;                      // 4000 * 16B = 64 KB
    unsigned* done = (unsigned*)((char*)d_ws + (size_t)nchunk * sizeof(float4));

    hipLaunchKernelGGL(osc_clear, dim3(1), dim3(64), 0, stream, done);
    hipLaunchKernelGGL(osc_pass1, dim3(256), dim3(256), 0, stream,
                       lsw, lfw, rs, snap, done, nchunk);
    const int threads = 256;
    const int blocks = (nchunk + threads - 1) / threads;
    hipLaunchKernelGGL(osc_pass2, dim3(blocks), dim3(threads), 0, stream,
                       lsw, lfw, rs, snap, out, steps, nchunk);
}

// Round 14
// 1733.138 us; speedup vs baseline: 2.5639x; 1.0112x over previous
//
#include <hip/hip_runtime.h>
#include <math.h>

// NestedOscillator — R8-exact two-pass scan (best measured: 1609 µs),
// consolidation round: K_STEPS 25 -> 50 (halves per-chunk bookkeeping,
// identical math), inner step reverted from R13's pk-asm (marshaling
// regressed) to R8's verified scalar form.
//
// Final model (R2-R13): lone-wave serial chain costs ~4 cyc/VALU-instruction;
// R8's 10-VALU branchless step = ~42 cyc/step is the floor. Closed escapes:
// cross-wave split (R5/R9), SALU routing (R6), dynamic branches (R10),
// dep-pipelining (R11), speculative fast chain (R12: 1-ulp parity equilibrium
// is permanent), packed VOP3P (R13: marshaling cost).
//
// Bitwise-exactness (absmax 0.0, verified R1-R13):
//  - np.mod(x,2pi), x in [0,4pi): conditional subtract is Sterbenz-exact.
//  - omega = (float)exp((double)log_omega) == numpy f32 exp.
//  - crossed(t) == slow-wrap during step t-1 (wrap => slow_t < ds < pi and
//    slow_{t-1} >= 2pi - ds > pi; no wrap => slow increases, can't cross).
//  - reset: nf*k (k=0.5) < 2pi -> reference's outer mod is identity;
//    non-crossed steps multiply by 1.0f (bit-exact, no denormals in [0,2pi)).

#define TWO_PI_F 6.28318530717958647692f
#define K_STEPS  50
#define HEAT_OUTER 3000

__device__ __forceinline__ void step_state(float& slow, float& fast, bool& wrap,
                                           float ds, float df, float k)
{
    const bool  crossed = wrap;
    const float ts = slow + ds;
    const float us = ts - TWO_PI_F;      // exact (Sterbenz) when ts >= 2pi
    const bool  w2 = (ts >= TWO_PI_F);
    const float tf = fast + df;
    const float uf = tf - TWO_PI_F;
    const bool  wfb = (tf >= TWO_PI_F);
    const float nf = wfb ? uf : tf;
    const float m  = crossed ? k : 1.0f;
    fast = nf * m;                       // *1.0f bit-exact (no denormals)
    slow = w2 ? us : ts;
    wrap = w2;
}

__global__ void osc_clear(unsigned* __restrict__ flag)
{
    if (threadIdx.x == 0) *flag = 0u;
}

__global__ __launch_bounds__(256, 1)
void osc_pass1(const float* __restrict__ lsw, const float* __restrict__ lfw,
               const float* __restrict__ rs, float4* __restrict__ snap,
               unsigned* __restrict__ flag, int nchunk)
{
    if (blockIdx.x == 0) {
        if (threadIdx.x != 0) return;    // chain thread alone in its wave
        const float ws = (float)exp((double)lsw[0]);
        const float wf = (float)exp((double)lfw[0]);
        const float k  = 1.0f - rs[0];
        const float ds = ws * 0.001f;
        const float df = wf * 0.001f;

        float slow = 0.0f, fast = 0.0f;
        bool wrap = false;               // t=0: prev=0 -> no crossing

        for (int c = 0; c < nchunk; ++c) {
            snap[c] = make_float4(slow, fast, wrap ? 1.0f : 0.0f, 0.0f);
#pragma unroll
            for (int i = 0; i < K_STEPS; ++i)
                step_state(slow, fast, wrap, ds, df, k);
        }
        __hip_atomic_store(flag, 1u, __ATOMIC_RELEASE, __HIP_MEMORY_SCOPE_AGENT);
    } else {
        // heater: keep clocks up (R7/R8: +10%); capped + flag-stopped
        float a0 = 1.00f + (float)(threadIdx.x & 7) * 0.125f;
        float a1 = 1.25f, a2 = 1.50f, a3 = 1.75f;
        const float b = 1.0000001f, cc = 1.0e-7f;
        for (int o = 0; o < HEAT_OUTER; ++o) {
#pragma unroll
            for (int i = 0; i < 256; ++i) {
                a0 = __builtin_fmaf(a0, b, cc);
                a1 = __builtin_fmaf(a1, b, cc);
                a2 = __builtin_fmaf(a2, b, cc);
                a3 = __builtin_fmaf(a3, b, cc);
            }
            asm volatile("" :: "v"(a0), "v"(a1), "v"(a2), "v"(a3));
            if (__hip_atomic_load(flag, __ATOMIC_ACQUIRE,
                                  __HIP_MEMORY_SCOPE_AGENT))
                break;
        }
        asm volatile("" :: "v"(a0), "v"(a1), "v"(a2), "v"(a3));
    }
}

__global__ __launch_bounds__(256)
void osc_pass2(const float* __restrict__ lsw, const float* __restrict__ lfw,
               const float* __restrict__ rs, const float4* __restrict__ snap,
               float* __restrict__ out, int steps, int nchunk)
{
    const int c = blockIdx.x * blockDim.x + threadIdx.x;
    if (c >= nchunk) return;

    const float ws = (float)exp((double)lsw[0]);
    const float wfr = (float)exp((double)lfw[0]);
    const float k  = 1.0f - rs[0];
    const float ds = ws * 0.001f;
    const float df = wfr * 0.001f;
    const float inv2pi = 0.15915494309189533577f;

    float4 s = snap[c];
    float slow = s.x, fast = s.y;
    bool wrap = (s.z != 0.0f);

    float* __restrict__ o_slow = out;
    float* __restrict__ o_fast = out + steps;
    float* __restrict__ o_fis  = out + 2 * steps;
    const int base = c * K_STEPS;

#pragma unroll 5
    for (int i = 0; i < K_STEPS; ++i) {
        const int t = base + i;
        if (t < steps) {
            o_slow[t] = slow;
            o_fast[t] = fast;
            o_fis[t]  = slow * inv2pi;
        }
        step_state(slow, fast, wrap, ds, df, k);
    }
}

extern "C" void kernel_launch(void* const* d_in, const int* in_sizes, int n_in,
                              void* d_out, int out_size, void* d_ws, size_t ws_size,
                              hipStream_t stream)
{
    const float* lsw = (const float*)d_in[0];
    const float* lfw = (const float*)d_in[1];
    const float* rs  = (const float*)d_in[2];
    float* out = (float*)d_out;
    const int steps  = out_size / 3;                     // 100000
    const int nchunk = (steps + K_STEPS - 1) / K_STEPS;  // 2000

    float4*   snap = (float4*)d_ws;                      // 2000 * 16B = 32 KB
    unsigned* flag = (unsigned*)((char*)d_ws + (size_t)nchunk * sizeof(float4));

    hipLaunchKernelGGL(osc_clear, dim3(1), dim3(64), 0, stream, flag);
    hipLaunchKernelGGL(osc_pass1, dim3(256), dim3(256), 0, stream,
                       lsw, lfw, rs, snap, flag, nchunk);
    const int threads = 256;
    const int blocks = (nchunk + threads - 1) / threads;
    hipLaunchKernelGGL(osc_pass2, dim3(blocks), dim3(threads), 0, stream,
                       lsw, lfw, rs, snap, out, steps, nchunk);
}